// Round 11
// baseline (197.085 us; speedup 1.0000x reference)
//
#include <hip/hip_runtime.h>

typedef unsigned short u16;
typedef short s16x8 __attribute__((ext_vector_type(8)));
typedef float f32x4 __attribute__((ext_vector_type(4)));

// ---------- scalar dtype helpers ----------
__device__ __forceinline__ u16 f2bf(float f) {
    union { float f; unsigned u; } v; v.f = f;
    unsigned r = v.u + 0x7FFFu + ((v.u >> 16) & 1u);   // RNE
    return (u16)(r >> 16);
}
__device__ __forceinline__ float bf2f(u16 h) {
    union { unsigned u; float f; } v; v.u = ((unsigned)h) << 16;
    return v.f;
}
__device__ __forceinline__ u16 f2h(float f) {
    _Float16 h = (_Float16)f;
    union { _Float16 h; u16 u; } v; v.h = h; return v.u;
}
__device__ __forceinline__ float h2f(u16 u) {
    union { u16 u; _Float16 h; } v; v.u = u; return (float)v.h;
}

// async global->LDS, 16B per lane; LDS dest = wave-uniform base + lane*16
__device__ __forceinline__ void gl_lds16(const u16* g, u16* l) {
    __builtin_amdgcn_global_load_lds(
        (const __attribute__((address_space(1))) void*)g,
        (__attribute__((address_space(3))) void*)l,
        16, 0, 0);
}

// ---------- fp32 -> bf16 convert ----------
__global__ __launch_bounds__(256) void f32_to_bf16(const float* __restrict__ in,
                                                   u16* __restrict__ out, int n) {
    int i = (blockIdx.x * 256 + threadIdx.x) * 4;
    int stride = gridDim.x * 256 * 4;
    for (; i < n; i += stride) {
        float4 v = *reinterpret_cast<const float4*>(in + i);
        ushort4 o;
        o.x = f2bf(v.x); o.y = f2bf(v.y); o.z = f2bf(v.z); o.w = f2bf(v.w);
        *reinterpret_cast<ushort4*>(out + i) = o;
    }
}

template <typename CT>
__device__ __forceinline__ void store_c(CT* p, float v) {
    if constexpr (__is_same(CT, u16))            *p = f2bf(v);
    else if constexpr (__is_same(CT, _Float16))  *p = (_Float16)v;
    else                                         *p = v;
}

// BK=32 swizzled LDS fragment read (verified R10: absmax OK, 0 conflicts).
// Row-major [row][32 u16]; 16B-slot s = fq ^ ((row>>1)&3) -> worst 2-way (free).
__device__ __forceinline__ s16x8 ldfrag32(const u16* base, int row, int fq) {
    return *reinterpret_cast<const s16x8*>(base + row * 32 + ((fq ^ ((row >> 1) & 3)) << 3));
}

#define MFMA16(a, b, c) __builtin_amdgcn_mfma_f32_16x16x32_bf16((a), (b), (c), 0, 0, 0)

// ================= unified bf16 GEMM, C = A @ B^T =================
// BM=256 x BNT, 8 waves (512 thr), wave tile 128 x BNT/4, BK=32, double-buffered
// LDS (BNT=256: 64KB -> 2 blk/CU; BNT=128: 48KB -> 3 blk/CU), R5/R6-proven
// 2-phase schedule (vmcnt -> barrier -> ds_read -> MFMA -> barrier -> stage t+2),
// pre-swizzled global source (both-sides rule).
// MODE 0: QKV, grid 384 1D XCD-banded; col<2048 -> qk, col>=2048 -> VT direct.
// MODE 1: S = Q@K^T, grid (16,8,4), keep bx <= 2*by+1 (exact causal cover).
// MODE 2: PV, grid (8,32): y -> batch=y&3, rowtile=7-(y>>2); kend=(rt+1)*256.
template <int MODE, int BNT, typename CT>
__global__ __launch_bounds__(512, 2)
void gemm_bt(const u16* __restrict__ A, const u16* __restrict__ B, CT* __restrict__ C,
             u16* __restrict__ VT,
             int K, int lda, int ldb, int ldc, long sA, long sB, long sC) {
    constexpr int NF = BNT / 64;           // n-frags per wave (4 or 2)
    constexpr int LB = BNT / 128;          // B loads per thread per step (2 or 1)
    constexpr int SB = 8192 + BNT * 32;    // u16 per LDS buffer

    int bx, by, bz;
    if (MODE == 0) {
        int bid = blockIdx.x;              // 384 blocks; HW: xcd = bid % 8
        int xcd = bid & 7, idx = bid >> 3; // 48 per XCD
        bx = idx % 12;
        by = xcd * 4 + idx / 12;           // each XCD owns 4 row bands (L2-resident)
        bz = 0;
    } else {
        bx = blockIdx.x; by = blockIdx.y; bz = blockIdx.z;
    }
    if (MODE == 1 && bx > 2 * by + 1) return;
    if (MODE == 2) { bz = blockIdx.y & 3; by = 7 - (int)(blockIdx.y >> 2); }
    A += (size_t)bz * sA; B += (size_t)bz * sB; C += (size_t)bz * sC;
    int kend = K;
    if (MODE == 2) kend = (by + 1) * 256;
    const int NT = kend >> 5;              // K-steps of 32

    __shared__ u16 lds[2 * SB];

    const int tid  = threadIdx.x;
    const int lane = tid & 63;
    const int wave = tid >> 6;             // 0..7
    const int wr = (wave >> 2) * 128;      // 0 or 128
    const int wc = (wave & 3) * (BNT / 4);
    const int fr = lane & 15;
    const int fq = lane >> 4;
    const int tm = by * 256, tn = bx * BNT;

    // staging: thread -> (row = j*128 + tid/4, 16B-slot = tid&3), col pre-swizzled
    const int srow = tid >> 2;             // 0..127
    const int slot = tid & 3;
    const u16* gA[2]; const u16* gB[LB];
#pragma unroll
    for (int j = 0; j < 2; ++j) {
        int row = j * 128 + srow;
        gA[j] = A + (size_t)(tm + row) * lda + (((slot ^ ((row >> 1) & 3))) << 3);
    }
#pragma unroll
    for (int j = 0; j < LB; ++j) {
        int row = j * 128 + srow;
        gB[j] = B + (size_t)(tn + row) * ldb + (((slot ^ ((row >> 1) & 3))) << 3);
    }

#define STAGE(b2, k0) do {                                                        \
    _Pragma("unroll") for (int j = 0; j < 2; ++j)                                 \
        gl_lds16(gA[j] + (k0), lds + (b2) * SB + j * 4096 + tid * 8);             \
    _Pragma("unroll") for (int j = 0; j < LB; ++j)                                \
        gl_lds16(gB[j] + (k0), lds + (b2) * SB + 8192 + j * 4096 + tid * 8);      \
  } while (0)

    f32x4 acc[8][NF];
#pragma unroll
    for (int m = 0; m < 8; ++m)
#pragma unroll
        for (int n = 0; n < NF; ++n) acc[m][n] = {0.f, 0.f, 0.f, 0.f};

    STAGE(0, 0);
    if (NT > 1) STAGE(1, 32);

    for (int t = 0; t < NT; ++t) {
        const int buf = t & 1;
        if (t + 1 < NT) {
            if constexpr (BNT == 256) asm volatile("s_waitcnt vmcnt(4)" ::: "memory");
            else                      asm volatile("s_waitcnt vmcnt(3)" ::: "memory");
        } else {
            asm volatile("s_waitcnt vmcnt(0)" ::: "memory");
        }
        __builtin_amdgcn_s_barrier();      // all waves' step-t loads landed
        __builtin_amdgcn_sched_barrier(0);

        const u16* Ab = lds + buf * SB;
        const u16* Bb = Ab + 8192;
        s16x8 bfr[NF];
#pragma unroll
        for (int n = 0; n < NF; ++n) bfr[n] = ldfrag32(Bb, wc + n * 16 + fr, fq);
        __builtin_amdgcn_s_setprio(1);
#pragma unroll
        for (int m = 0; m < 8; ++m) {
            s16x8 a = ldfrag32(Ab, wr + m * 16 + fr, fq);
#pragma unroll
            for (int n = 0; n < NF; ++n)
                acc[m][n] = MFMA16(a, bfr[n], acc[m][n]);
        }
        __builtin_amdgcn_s_setprio(0);
        __builtin_amdgcn_sched_barrier(0);
        __builtin_amdgcn_s_barrier();      // buf free for t+2 staging
        if (t + 2 < NT) STAGE(buf, (t + 2) << 5);
    }
#undef STAGE

    // epilogue: D row=(lane>>4)*4+r, col=lane&15 (m89-verified)
    if (MODE == 0 && tn >= 2048) {
#pragma unroll
        for (int m = 0; m < 8; ++m)
#pragma unroll
            for (int n = 0; n < NF; ++n)
#pragma unroll
                for (int r = 0; r < 4; ++r) {
                    int row = tm + wr + m * 16 + fq * 4 + r;
                    int col = tn + wc + n * 16 + fr;
                    VT[((size_t)(row >> 11)) * 2097152 + (size_t)(col - 2048) * 2048 + (row & 2047)]
                        = f2bf(acc[m][n][r]);
                }
    } else {
#pragma unroll
        for (int m = 0; m < 8; ++m)
#pragma unroll
            for (int n = 0; n < NF; ++n)
#pragma unroll
                for (int r = 0; r < 4; ++r) {
                    int row = tm + wr + m * 16 + fq * 4 + r;
                    int col = tn + wc + n * 16 + fr;
                    store_c(&C[(size_t)row * ldc + col], acc[m][n][r]);
                }
    }
}

// ---------- trig table: trig[t][d] = cos, trig[t][512+d] = sin (fp16) ----------
__global__ __launch_bounds__(256)
void trig_table(u16* __restrict__ trig) {
    const int t = blockIdx.x;
    const float L = 0.025952563241307517f;  // log2(10000)/512
    u16* row = trig + (size_t)t * 1024;
#pragma unroll
    for (int i = 0; i < 2; ++i) {
        int d = threadIdx.x + i * 256;
        float invf = exp2f(-(float)d * L);
        float ang = (float)t * invf;
        float s, c;
        sincosf(ang, &s, &c);
        row[d] = f2h(c);
        row[512 + d] = f2h(s);
    }
}

// ---------- RoPE + L2 norm * sqk*32, in-place on qk[8192][2048] ----------
__global__ __launch_bounds__(256)
void rope_norm(u16* __restrict__ qk, const float* __restrict__ sqk,
               const u16* __restrict__ trig) {
    const int row = blockIdx.x;        // b*2048 + t
    const int t = row & 2047;
    u16* qp = qk + (size_t)row * 2048;
    u16* kp = qp + 1024;
    const u16* tb = trig + (size_t)t * 1024;
    const int d = threadIdx.x << 1;    // 0,2,...,510

    union U2 { uint u; u16 h[2]; };
    U2 qc0, qc1, kc0, kc1, cc, ss;
    qc0.u = *reinterpret_cast<const uint*>(qp + d);
    qc1.u = *reinterpret_cast<const uint*>(qp + 512 + d);
    kc0.u = *reinterpret_cast<const uint*>(kp + d);
    kc1.u = *reinterpret_cast<const uint*>(kp + 512 + d);
    cc.u  = *reinterpret_cast<const uint*>(tb + d);
    ss.u  = *reinterpret_cast<const uint*>(tb + 512 + d);

    float nq0[2], nq1[2], nk0[2], nk1[2];
    float ssq_q = 0.f, ssq_k = 0.f;
#pragma unroll
    for (int j = 0; j < 2; ++j) {
        float c = h2f(cc.h[j]), s = h2f(ss.h[j]);
        float q0 = bf2f(qc0.h[j]), q1 = bf2f(qc1.h[j]);
        float k0 = bf2f(kc0.h[j]), k1 = bf2f(kc1.h[j]);
        nq0[j] = q0 * c - q1 * s;
        nq1[j] = q1 * c + q0 * s;
        nk0[j] = k0 * c - k1 * s;
        nk1[j] = k1 * c + k0 * s;
        ssq_q += nq0[j] * nq0[j] + nq1[j] * nq1[j];
        ssq_k += nk0[j] * nk0[j] + nk1[j] * nk1[j];
    }

#pragma unroll
    for (int off = 32; off; off >>= 1) {
        ssq_q += __shfl_xor(ssq_q, off);
        ssq_k += __shfl_xor(ssq_k, off);
    }
    __shared__ float red[8];
    int wave = threadIdx.x >> 6, lane = threadIdx.x & 63;
    if (lane == 0) { red[wave] = ssq_q; red[4 + wave] = ssq_k; }
    __syncthreads();
    float rq = rsqrtf(red[0] + red[1] + red[2] + red[3]);
    float rk = rsqrtf(red[4] + red[5] + red[6] + red[7]);

    float2 sq0 = *reinterpret_cast<const float2*>(sqk + d);
    float2 sq1 = *reinterpret_cast<const float2*>(sqk + 512 + d);
    float s0[2] = {sq0.x * 32.f, sq0.y * 32.f};
    float s1[2] = {sq1.x * 32.f, sq1.y * 32.f};

    U2 oq0, oq1, ok0, ok1;
#pragma unroll
    for (int j = 0; j < 2; ++j) {
        oq0.h[j] = f2bf(nq0[j] * rq * s0[j]);
        oq1.h[j] = f2bf(nq1[j] * rq * s1[j]);
        ok0.h[j] = f2bf(nk0[j] * rk * s0[j]);
        ok1.h[j] = f2bf(nk1[j] * rk * s1[j]);
    }
    *reinterpret_cast<uint*>(qp + d)       = oq0.u;
    *reinterpret_cast<uint*>(qp + 512 + d) = oq1.u;
    *reinterpret_cast<uint*>(kp + d)       = ok0.u;
    *reinterpret_cast<uint*>(kp + 512 + d) = ok1.u;
}

// ---------- in-place causal softmax over fp16 S rows -> bf16 P (same bytes) ----------
// Writes cols [0, ((r>>8)+1)*256) — 256-granular, matching PV's 256-row K limits.
__global__ __launch_bounds__(256)
void softmax_inplace(u16* __restrict__ Sbase) {
    const int r = blockIdx.x;
    const int b = blockIdx.y;
    u16* row = Sbase + (size_t)b * 4194304 + (size_t)r * 2048;
    const int n = r + 1;
    const int kcap = ((r >> 8) + 1) << 8;
    const int tid = threadIdx.x;
    const bool act = (tid * 8) < kcap;

    union { uint4 u; u16 h[8]; } U;
    if (act) U.u = *reinterpret_cast<const uint4*>(row + tid * 8);
    float v[8];
    float m = -1e30f;
#pragma unroll
    for (int i = 0; i < 8; ++i) {
        int c = tid * 8 + i;
        v[i] = (act && c < n) ? h2f(U.h[i]) : -1e30f;
        m = fmaxf(m, v[i]);
    }
#pragma unroll
    for (int off = 32; off; off >>= 1) m = fmaxf(m, __shfl_xor(m, off));
    __shared__ float redm[4], redsum[4];
    int wave = tid >> 6, lane = tid & 63;
    if (lane == 0) redm[wave] = m;
    __syncthreads();
    m = fmaxf(fmaxf(redm[0], redm[1]), fmaxf(redm[2], redm[3]));
    float M = 32.f * m;

    float sum = 0.f;
#pragma unroll
    for (int i = 0; i < 8; ++i) {
        int c = tid * 8 + i;
        float e = (v[i] > -1e29f) ? __expf(32.f * v[i] - M) : 0.f;
        if (c >= n) e = 0.f;
        v[i] = e;
        sum += e;
    }
#pragma unroll
    for (int off = 32; off; off >>= 1) sum += __shfl_xor(sum, off);
    if (lane == 0) redsum[wave] = sum;
    __syncthreads();
    sum = redsum[0] + redsum[1] + redsum[2] + redsum[3];
    float inv = 1.f / sum;

    if (act) {
        union { uint4 u; u16 h[8]; } O;
#pragma unroll
        for (int i = 0; i < 8; ++i) O.h[i] = f2bf(v[i] * inv);
        *reinterpret_cast<uint4*>(row + tid * 8) = O.u;
    }
}

// ---------- host launcher ----------
extern "C" void kernel_launch(void* const* d_in, const int* in_sizes, int n_in,
                              void* d_out, int out_size, void* d_ws, size_t ws_size,
                              hipStream_t stream) {
    const float* x   = (const float*)d_in[0];   // [4,2048,1024]
    const float* w   = (const float*)d_in[1];   // [3072,1024]
    const float* sqk = (const float*)d_in[2];   // [1024]
    float* out = (float*)d_out;

    const size_t SZ_XB  = (size_t)8192 * 1024 * 2;
    const size_t SZ_WB  = (size_t)3072 * 1024 * 2;
    const size_t SZ_QK  = (size_t)8192 * 2048 * 2;
    const size_t SZ_VT  = (size_t)4 * 1024 * 2048 * 2;
    const size_t SZ_S   = (size_t)4 * 2048 * 2048 * 2;    // fp16
    const size_t SZ_TR  = (size_t)2048 * 1024 * 2;
    if (ws_size < SZ_XB + SZ_WB + SZ_QK + SZ_VT + SZ_S + SZ_TR) return;

    char* ws = (char*)d_ws;
    u16* xb   = (u16*)ws;  ws += SZ_XB;
    u16* wb   = (u16*)ws;  ws += SZ_WB;
    u16* qk   = (u16*)ws;  ws += SZ_QK;
    u16* VT   = (u16*)ws;  ws += SZ_VT;
    u16* S    = (u16*)ws;  ws += SZ_S;
    u16* trig = (u16*)ws;

    f32_to_bf16<<<2048, 256, 0, stream>>>(x, xb, 8192 * 1024);
    f32_to_bf16<<<768, 256, 0, stream>>>(w, wb, 3072 * 1024);
    trig_table<<<2048, 256, 0, stream>>>(trig);

    // QKV: qk[8192][2048] (Q|K) + VT[b][1024][2048] (V^T direct), 256x256 BK=32
    gemm_bt<0, 256, u16><<<dim3(384, 1, 1), 512, 0, stream>>>(
        xb, wb, qk, VT, 1024, 1024, 1024, 2048, 0, 0, 0);

    rope_norm<<<8192, 256, 0, stream>>>(qk, sqk, trig);

    // S = Q @ K^T, 256M x 128N, exact causal tile cover, fp16 out
    gemm_bt<1, 128, _Float16><<<dim3(16, 8, 4), 512, 0, stream>>>(
        qk, qk + 1024, (_Float16*)S, nullptr, 1024, 2048, 2048, 2048,
        (long)2048 * 2048, (long)2048 * 2048, (long)2048 * 2048);

    softmax_inplace<<<dim3(2048, 4), 256, 0, stream>>>(S);

    // out = P @ V, 256M x 128N, longest-first row tiles
    gemm_bt<2, 128, float><<<dim3(8, 32, 1), 512, 0, stream>>>(
        S, VT, out, nullptr, 2048, 2048, 2048, 1024,
        (long)2048 * 2048, (long)1024 * 2048, (long)2048 * 1024);
}

// Round 12
// 157.077 us; speedup vs baseline: 1.2547x; 1.2547x over previous
//
#include <hip/hip_runtime.h>

typedef unsigned short u16;
typedef short s16x8 __attribute__((ext_vector_type(8)));
typedef float f32x4 __attribute__((ext_vector_type(4)));

// ---------- scalar dtype helpers ----------
__device__ __forceinline__ u16 f2bf(float f) {
    union { float f; unsigned u; } v; v.f = f;
    unsigned r = v.u + 0x7FFFu + ((v.u >> 16) & 1u);   // RNE
    return (u16)(r >> 16);
}
__device__ __forceinline__ float bf2f(u16 h) {
    union { unsigned u; float f; } v; v.u = ((unsigned)h) << 16;
    return v.f;
}
__device__ __forceinline__ u16 f2h(float f) {
    _Float16 h = (_Float16)f;
    union { _Float16 h; u16 u; } v; v.h = h; return v.u;
}
__device__ __forceinline__ float h2f(u16 u) {
    union { u16 u; _Float16 h; } v; v.u = u; return (float)v.h;
}

// async global->LDS, 16B per lane; LDS dest = wave-uniform base + lane*16
__device__ __forceinline__ void gl_lds16(const u16* g, u16* l) {
    __builtin_amdgcn_global_load_lds(
        (const __attribute__((address_space(1))) void*)g,
        (__attribute__((address_space(3))) void*)l,
        16, 0, 0);
}

template <typename CT>
__device__ __forceinline__ void store_c(CT* p, float v) {
    if constexpr (__is_same(CT, u16))            *p = f2bf(v);
    else if constexpr (__is_same(CT, _Float16))  *p = (_Float16)v;
    else                                         *p = v;
}

// BK=64 swizzled LDS fragment read (R4-R6 verified): row-major [row][64 u16],
// byte col cb = ((kk<<6)+(fq<<4)) ^ ((row&7)<<4).
__device__ __forceinline__ s16x8 ldfrag(const u16* base, int row, int kk, int fq) {
    int cb = ((kk << 6) + (fq << 4)) ^ ((row & 7) << 4);
    return *reinterpret_cast<const s16x8*>(base + row * 64 + (cb >> 1));
}

#define MFMA16(a, b, c) __builtin_amdgcn_mfma_f32_16x16x32_bf16((a), (b), (c), 0, 0, 0)

// ---------- fused prep: convert x, convert w, build trig table ----------
// grid 4864 x 256: [0,2048) x-convert, [2048,2816) w-convert, [2816,4864) trig.
__global__ __launch_bounds__(256)
void prep(const float* __restrict__ x, const float* __restrict__ w,
          u16* __restrict__ xb, u16* __restrict__ wb, u16* __restrict__ trig) {
    const int bid = blockIdx.x;
    if (bid < 2048) {
        int i = (bid * 256 + threadIdx.x) * 4;
        const int stride = 2048 * 256 * 4;
        for (; i < 8192 * 1024; i += stride) {
            float4 v = *reinterpret_cast<const float4*>(x + i);
            ushort4 o;
            o.x = f2bf(v.x); o.y = f2bf(v.y); o.z = f2bf(v.z); o.w = f2bf(v.w);
            *reinterpret_cast<ushort4*>(xb + i) = o;
        }
    } else if (bid < 2816) {
        int i = ((bid - 2048) * 256 + threadIdx.x) * 4;
        const int stride = 768 * 256 * 4;
        for (; i < 3072 * 1024; i += stride) {
            float4 v = *reinterpret_cast<const float4*>(w + i);
            ushort4 o;
            o.x = f2bf(v.x); o.y = f2bf(v.y); o.z = f2bf(v.z); o.w = f2bf(v.w);
            *reinterpret_cast<ushort4*>(wb + i) = o;
        }
    } else {
        const int t = bid - 2816;
        const float L = 0.025952563241307517f;  // log2(10000)/512
        u16* row = trig + (size_t)t * 1024;
#pragma unroll
        for (int i = 0; i < 2; ++i) {
            int d = threadIdx.x + i * 256;
            float invf = exp2f(-(float)d * L);
            float ang = (float)t * invf;
            float s, c;
            sincosf(ang, &s, &c);
            row[d] = f2h(c);
            row[512 + d] = f2h(s);
        }
    }
}

// ================= unified bf16 GEMM, C = A @ B^T (R5/R6-verified template) ========
// 128x128 tile, 8 waves (512 thr), wave tile 64x32, BK=64, double-buffered LDS
// (64KB -> 2 blocks/CU), counted vmcnt, raw barriers, XOR-swizzle (both-sides).
// MODE 0: QKV, grid 1536 1D XCD-banded; col<2048 -> qk[8192][2048], else VT direct.
// MODE 1: S = Q@K^T causal, grid (16,16,4), skip bx>by.
// MODE 2: PV, grid (8,64): y decodes (batch=y&3, rowtile=15-(y>>2)), longest-first,
//         kend=(rowtile+1)*128.
template <int MODE, typename CT>
__global__ __launch_bounds__(512)
void gemm_bt(const u16* __restrict__ A, const u16* __restrict__ B, CT* __restrict__ C,
             u16* __restrict__ VT,
             int K, int lda, int ldb, int ldc, long sA, long sB, long sC) {
    int bx, by, bz;
    if (MODE == 0) {
        int bid = blockIdx.x;              // 1536 blocks; HW: xcd = bid % 8
        int xcd = bid & 7, idx = bid >> 3; // 192 per XCD
        int r = idx >> 6, w2 = idx & 63;   // 3 regions of 8bx x 8by
        bx = r * 8 + (w2 & 7);
        by = xcd * 8 + (w2 >> 3);
        bz = 0;
    } else {
        bx = blockIdx.x; by = blockIdx.y; bz = blockIdx.z;
    }
    if (MODE == 1 && bx > by) return;
    if (MODE == 2) { bz = blockIdx.y & 3; by = 15 - (int)(blockIdx.y >> 2); }
    A += (size_t)bz * sA; B += (size_t)bz * sB; C += (size_t)bz * sC;
    int kend = K;
    if (MODE == 2) { int kl = (by + 1) * 128; kend = kl < K ? kl : K; }
    const int NT = kend >> 6;              // K-steps of 64

    __shared__ u16 lds[32768];             // 2 bufs x [A 8192 u16 | B 8192 u16]

    const int tid  = threadIdx.x;
    const int lane = tid & 63;
    const int wave = tid >> 6;             // 0..7
    const int wr = (wave >> 2) * 64;       // 0 or 64
    const int wc = (wave & 3) * 32;        // 0/32/64/96
    const int fr = lane & 15;
    const int fq = lane >> 4;
    const int tm = by * 128, tn = bx * 128;

    // staging: 4 x 16B per thread per K-step (2 A + 2 B), pre-swizzled source col
    const int srow = tid >> 3;                                  // 0..63
    const int gco  = (((tid & 7) ^ (srow & 7)) << 3);           // u16 col
    const u16* aR[2]; const u16* bR[2];
#pragma unroll
    for (int j = 0; j < 2; ++j) {
        aR[j] = A + (size_t)(tm + j * 64 + srow) * lda + gco;
        bR[j] = B + (size_t)(tn + j * 64 + srow) * ldb + gco;
    }

#define STAGE(b2, k0) do {                                                        \
    _Pragma("unroll") for (int j = 0; j < 2; ++j)                                 \
        gl_lds16(aR[j] + (k0), lds + (b2) * 16384 + j * 4096 + wave * 512);       \
    _Pragma("unroll") for (int j = 0; j < 2; ++j)                                 \
        gl_lds16(bR[j] + (k0), lds + (b2) * 16384 + 8192 + j * 4096 + wave * 512);\
  } while (0)

    f32x4 acc[4][2];
#pragma unroll
    for (int m = 0; m < 4; ++m)
#pragma unroll
        for (int n = 0; n < 2; ++n) acc[m][n] = {0.f, 0.f, 0.f, 0.f};

    STAGE(0, 0);
    if (NT > 1) STAGE(1, 64);

    for (int t = 0; t < NT; ++t) {
        const int buf = t & 1;
        if (t + 1 < NT) { asm volatile("s_waitcnt vmcnt(4)" ::: "memory"); }
        else            { asm volatile("s_waitcnt vmcnt(0)" ::: "memory"); }
        __builtin_amdgcn_s_barrier();
        __builtin_amdgcn_sched_barrier(0);

        const u16* Ab = lds + buf * 16384;
        const u16* Bb = Ab + 8192;
        s16x8 bf0[2], bf1[2];
#pragma unroll
        for (int n = 0; n < 2; ++n) {
            bf0[n] = ldfrag(Bb, wc + n * 16 + fr, 0, fq);
            bf1[n] = ldfrag(Bb, wc + n * 16 + fr, 1, fq);
        }
        __builtin_amdgcn_s_setprio(1);
#pragma unroll
        for (int m = 0; m < 4; ++m) {
            s16x8 a0 = ldfrag(Ab, wr + m * 16 + fr, 0, fq);
            s16x8 a1 = ldfrag(Ab, wr + m * 16 + fr, 1, fq);
#pragma unroll
            for (int n = 0; n < 2; ++n) {
                acc[m][n] = MFMA16(a0, bf0[n], acc[m][n]);
                acc[m][n] = MFMA16(a1, bf1[n], acc[m][n]);
            }
        }
        __builtin_amdgcn_s_setprio(0);
        __builtin_amdgcn_sched_barrier(0);
        __builtin_amdgcn_s_barrier();
        if (t + 2 < NT) STAGE(buf, (t + 2) << 6);
    }
#undef STAGE

    // epilogue: D row=(lane>>4)*4+r, col=lane&15 (m89-verified)
    if (MODE == 0 && tn >= 2048) {
        // V column-tiles: write transposed into VT[b][col-2048][t]
#pragma unroll
        for (int m = 0; m < 4; ++m)
#pragma unroll
            for (int n = 0; n < 2; ++n)
#pragma unroll
                for (int r = 0; r < 4; ++r) {
                    int row = tm + wr + m * 16 + fq * 4 + r;
                    int col = tn + wc + n * 16 + fr;
                    VT[((size_t)(row >> 11)) * 2097152 + (size_t)(col - 2048) * 2048 + (row & 2047)]
                        = f2bf(acc[m][n][r]);
                }
    } else {
#pragma unroll
        for (int m = 0; m < 4; ++m)
#pragma unroll
            for (int n = 0; n < 2; ++n)
#pragma unroll
                for (int r = 0; r < 4; ++r) {
                    int row = tm + wr + m * 16 + fq * 4 + r;
                    int col = tn + wc + n * 16 + fr;
                    store_c(&C[(size_t)row * ldc + col], acc[m][n][r]);
                }
    }
}

// ---------- RoPE + L2 norm * sqk*32, in-place on qk[8192][2048] ----------
__global__ __launch_bounds__(256)
void rope_norm(u16* __restrict__ qk, const float* __restrict__ sqk,
               const u16* __restrict__ trig) {
    const int row = blockIdx.x;        // b*2048 + t
    const int t = row & 2047;
    u16* qp = qk + (size_t)row * 2048;
    u16* kp = qp + 1024;
    const u16* tb = trig + (size_t)t * 1024;
    const int d = threadIdx.x << 1;    // 0,2,...,510

    union U2 { uint u; u16 h[2]; };
    U2 qc0, qc1, kc0, kc1, cc, ss;
    qc0.u = *reinterpret_cast<const uint*>(qp + d);
    qc1.u = *reinterpret_cast<const uint*>(qp + 512 + d);
    kc0.u = *reinterpret_cast<const uint*>(kp + d);
    kc1.u = *reinterpret_cast<const uint*>(kp + 512 + d);
    cc.u  = *reinterpret_cast<const uint*>(tb + d);
    ss.u  = *reinterpret_cast<const uint*>(tb + 512 + d);

    float nq0[2], nq1[2], nk0[2], nk1[2];
    float ssq_q = 0.f, ssq_k = 0.f;
#pragma unroll
    for (int j = 0; j < 2; ++j) {
        float c = h2f(cc.h[j]), s = h2f(ss.h[j]);
        float q0 = bf2f(qc0.h[j]), q1 = bf2f(qc1.h[j]);
        float k0 = bf2f(kc0.h[j]), k1 = bf2f(kc1.h[j]);
        nq0[j] = q0 * c - q1 * s;
        nq1[j] = q1 * c + q0 * s;
        nk0[j] = k0 * c - k1 * s;
        nk1[j] = k1 * c + k0 * s;
        ssq_q += nq0[j] * nq0[j] + nq1[j] * nq1[j];
        ssq_k += nk0[j] * nk0[j] + nk1[j] * nk1[j];
    }

#pragma unroll
    for (int off = 32; off; off >>= 1) {
        ssq_q += __shfl_xor(ssq_q, off);
        ssq_k += __shfl_xor(ssq_k, off);
    }
    __shared__ float red[8];
    int wave = threadIdx.x >> 6, lane = threadIdx.x & 63;
    if (lane == 0) { red[wave] = ssq_q; red[4 + wave] = ssq_k; }
    __syncthreads();
    float rq = rsqrtf(red[0] + red[1] + red[2] + red[3]);
    float rk = rsqrtf(red[4] + red[5] + red[6] + red[7]);

    float2 sq0 = *reinterpret_cast<const float2*>(sqk + d);
    float2 sq1 = *reinterpret_cast<const float2*>(sqk + 512 + d);
    float s0[2] = {sq0.x * 32.f, sq0.y * 32.f};
    float s1[2] = {sq1.x * 32.f, sq1.y * 32.f};

    U2 oq0, oq1, ok0, ok1;
#pragma unroll
    for (int j = 0; j < 2; ++j) {
        oq0.h[j] = f2bf(nq0[j] * rq * s0[j]);
        oq1.h[j] = f2bf(nq1[j] * rq * s1[j]);
        ok0.h[j] = f2bf(nk0[j] * rk * s0[j]);
        ok1.h[j] = f2bf(nk1[j] * rk * s1[j]);
    }
    *reinterpret_cast<uint*>(qp + d)       = oq0.u;
    *reinterpret_cast<uint*>(qp + 512 + d) = oq1.u;
    *reinterpret_cast<uint*>(kp + d)       = ok0.u;
    *reinterpret_cast<uint*>(kp + 512 + d) = ok1.u;
}

// ---------- in-place causal softmax over fp16 S rows -> bf16 P (same bytes) ----------
// Writes cols [0, ((r>>7)+1)*128) — 128-granular, matching PV's 128-row K limits.
__global__ __launch_bounds__(256)
void softmax_inplace(u16* __restrict__ Sbase) {
    const int r = blockIdx.x;
    const int b = blockIdx.y;
    u16* row = Sbase + (size_t)b * 4194304 + (size_t)r * 2048;
    const int n = r + 1;
    const int kcap = ((r >> 7) + 1) << 7;
    const int tid = threadIdx.x;
    const bool act = (tid * 8) < kcap;

    union { uint4 u; u16 h[8]; } U;
    if (act) U.u = *reinterpret_cast<const uint4*>(row + tid * 8);
    float v[8];
    float m = -1e30f;
#pragma unroll
    for (int i = 0; i < 8; ++i) {
        int c = tid * 8 + i;
        v[i] = (act && c < n) ? h2f(U.h[i]) : -1e30f;
        m = fmaxf(m, v[i]);
    }
#pragma unroll
    for (int off = 32; off; off >>= 1) m = fmaxf(m, __shfl_xor(m, off));
    __shared__ float redm[4], redsum[4];
    int wave = tid >> 6, lane = tid & 63;
    if (lane == 0) redm[wave] = m;
    __syncthreads();
    m = fmaxf(fmaxf(redm[0], redm[1]), fmaxf(redm[2], redm[3]));
    float M = 32.f * m;

    float sum = 0.f;
#pragma unroll
    for (int i = 0; i < 8; ++i) {
        int c = tid * 8 + i;
        float e = (v[i] > -1e29f) ? __expf(32.f * v[i] - M) : 0.f;
        if (c >= n) e = 0.f;
        v[i] = e;
        sum += e;
    }
#pragma unroll
    for (int off = 32; off; off >>= 1) sum += __shfl_xor(sum, off);
    if (lane == 0) redsum[wave] = sum;
    __syncthreads();
    sum = redsum[0] + redsum[1] + redsum[2] + redsum[3];
    float inv = 1.f / sum;

    if (act) {
        union { uint4 u; u16 h[8]; } O;
#pragma unroll
        for (int i = 0; i < 8; ++i) O.h[i] = f2bf(v[i] * inv);
        *reinterpret_cast<uint4*>(row + tid * 8) = O.u;
    }
}

// ---------- host launcher ----------
extern "C" void kernel_launch(void* const* d_in, const int* in_sizes, int n_in,
                              void* d_out, int out_size, void* d_ws, size_t ws_size,
                              hipStream_t stream) {
    const float* x   = (const float*)d_in[0];   // [4,2048,1024]
    const float* w   = (const float*)d_in[1];   // [3072,1024]
    const float* sqk = (const float*)d_in[2];   // [1024]
    float* out = (float*)d_out;

    const size_t SZ_XB  = (size_t)8192 * 1024 * 2;
    const size_t SZ_WB  = (size_t)3072 * 1024 * 2;
    const size_t SZ_QK  = (size_t)8192 * 2048 * 2;
    const size_t SZ_VT  = (size_t)4 * 1024 * 2048 * 2;
    const size_t SZ_S   = (size_t)4 * 2048 * 2048 * 2;    // fp16
    const size_t SZ_TR  = (size_t)2048 * 1024 * 2;
    if (ws_size < SZ_XB + SZ_WB + SZ_QK + SZ_VT + SZ_S + SZ_TR) return;

    char* ws = (char*)d_ws;
    u16* xb   = (u16*)ws;  ws += SZ_XB;
    u16* wb   = (u16*)ws;  ws += SZ_WB;
    u16* qk   = (u16*)ws;  ws += SZ_QK;
    u16* VT   = (u16*)ws;  ws += SZ_VT;
    u16* S    = (u16*)ws;  ws += SZ_S;
    u16* trig = (u16*)ws;

    // fused prep: x->bf16, w->bf16, trig table
    prep<<<4864, 256, 0, stream>>>(x, w, xb, wb, trig);

    // QKV: qk[8192][2048] (Q|K) + VT[b][1024][2048] (V^T direct)
    gemm_bt<0, u16><<<dim3(1536, 1, 1), 512, 0, stream>>>(
        xb, wb, qk, VT, 1024, 1024, 1024, 2048, 0, 0, 0);

    rope_norm<<<8192, 256, 0, stream>>>(qk, sqk, trig);

    // S = Q @ K^T, causal 128^2 tiles, fp16
    gemm_bt<1, _Float16><<<dim3(16, 16, 4), 512, 0, stream>>>(
        qk, qk + 1024, (_Float16*)S, nullptr, 1024, 2048, 2048, 2048,
        (long)2048 * 2048, (long)2048 * 2048, (long)2048 * 2048);

    softmax_inplace<<<dim3(2048, 4), 256, 0, stream>>>(S);

    // out = P @ V, 128^2 tiles, longest-first over row tiles
    gemm_bt<2, float><<<dim3(8, 64, 1), 512, 0, stream>>>(
        S, VT, out, nullptr, 2048, 2048, 2048, 1024,
        (long)2048 * 2048, (long)1024 * 2048, (long)2048 * 1024);
}

// Round 13
// 155.842 us; speedup vs baseline: 1.2646x; 1.0079x over previous
//
#include <hip/hip_runtime.h>

typedef unsigned short u16;
typedef short s16x8 __attribute__((ext_vector_type(8)));
typedef float f32x4 __attribute__((ext_vector_type(4)));

// ---------- scalar dtype helpers ----------
__device__ __forceinline__ u16 f2bf(float f) {
    union { float f; unsigned u; } v; v.f = f;
    unsigned r = v.u + 0x7FFFu + ((v.u >> 16) & 1u);   // RNE
    return (u16)(r >> 16);
}
__device__ __forceinline__ float bf2f(u16 h) {
    union { unsigned u; float f; } v; v.u = ((unsigned)h) << 16;
    return v.f;
}
__device__ __forceinline__ u16 f2h(float f) {
    _Float16 h = (_Float16)f;
    union { _Float16 h; u16 u; } v; v.h = h; return v.u;
}
__device__ __forceinline__ float h2f(u16 u) {
    union { u16 u; _Float16 h; } v; v.u = u; return (float)v.h;
}

// async global->LDS, 16B per lane; LDS dest = wave-uniform base + lane*16
__device__ __forceinline__ void gl_lds16(const u16* g, u16* l) {
    __builtin_amdgcn_global_load_lds(
        (const __attribute__((address_space(1))) void*)g,
        (__attribute__((address_space(3))) void*)l,
        16, 0, 0);
}

template <typename CT>
__device__ __forceinline__ void store_c(CT* p, float v) {
    if constexpr (__is_same(CT, u16))            *p = f2bf(v);
    else if constexpr (__is_same(CT, _Float16))  *p = (_Float16)v;
    else                                         *p = v;
}

// BK=64 swizzled LDS fragment read (R4-R12 verified): row-major [row][64 u16],
// byte col cb = ((kk<<6)+(fq<<4)) ^ ((row&7)<<4).
__device__ __forceinline__ s16x8 ldfrag(const u16* base, int row, int kk, int fq) {
    int cb = ((kk << 6) + (fq << 4)) ^ ((row & 7) << 4);
    return *reinterpret_cast<const s16x8*>(base + row * 64 + (cb >> 1));
}

#define MFMA16(a, b, c) __builtin_amdgcn_mfma_f32_16x16x32_bf16((a), (b), (c), 0, 0, 0)

// ---------- fused prep: convert x, convert w, build trig table ----------
__global__ __launch_bounds__(256)
void prep(const float* __restrict__ x, const float* __restrict__ w,
          u16* __restrict__ xb, u16* __restrict__ wb, u16* __restrict__ trig) {
    const int bid = blockIdx.x;
    if (bid < 2048) {
        int i = (bid * 256 + threadIdx.x) * 4;
        const int stride = 2048 * 256 * 4;
        for (; i < 8192 * 1024; i += stride) {
            float4 v = *reinterpret_cast<const float4*>(x + i);
            ushort4 o;
            o.x = f2bf(v.x); o.y = f2bf(v.y); o.z = f2bf(v.z); o.w = f2bf(v.w);
            *reinterpret_cast<ushort4*>(xb + i) = o;
        }
    } else if (bid < 2816) {
        int i = ((bid - 2048) * 256 + threadIdx.x) * 4;
        const int stride = 768 * 256 * 4;
        for (; i < 3072 * 1024; i += stride) {
            float4 v = *reinterpret_cast<const float4*>(w + i);
            ushort4 o;
            o.x = f2bf(v.x); o.y = f2bf(v.y); o.z = f2bf(v.z); o.w = f2bf(v.w);
            *reinterpret_cast<ushort4*>(wb + i) = o;
        }
    } else {
        const int t = bid - 2816;
        const float L = 0.025952563241307517f;  // log2(10000)/512
        u16* row = trig + (size_t)t * 1024;
#pragma unroll
        for (int i = 0; i < 2; ++i) {
            int d = threadIdx.x + i * 256;
            float invf = exp2f(-(float)d * L);
            float ang = (float)t * invf;
            float s, c;
            sincosf(ang, &s, &c);
            row[d] = f2h(c);
            row[512 + d] = f2h(s);
        }
    }
}

// ================= unified bf16 GEMM, C = A @ B^T =================
// 128x128 tile, 4 waves (256 thr), wave tile 64x64 (acc[4][4]), BK=64,
// double-buffered LDS (64KB -> 2 blocks/CU), R5-R12-proven 2-phase schedule,
// XOR-swizzle both-sides. LDS reads halved vs 64x32 wave tile (0.0305 B/FLOP).
// MODE 0: QKV, grid 1536 1D XCD-banded; col<2048 -> qk[8192][2048], else VT direct.
// MODE 1: S = Q@K^T causal, grid (16,16,4), skip bx>by.
// MODE 2: PV, grid (8,64): y decodes (batch=y&3, rowtile=15-(y>>2)), longest-first,
//         kend=(rowtile+1)*128.
template <int MODE, typename CT>
__global__ __launch_bounds__(256, 2)
void gemm_bt(const u16* __restrict__ A, const u16* __restrict__ B, CT* __restrict__ C,
             u16* __restrict__ VT,
             int K, int lda, int ldb, int ldc, long sA, long sB, long sC) {
    int bx, by, bz;
    if (MODE == 0) {
        int bid = blockIdx.x;              // 1536 blocks; HW: xcd = bid % 8
        int xcd = bid & 7, idx = bid >> 3; // 192 per XCD
        int r = idx >> 6, w2 = idx & 63;   // 3 regions of 8bx x 8by
        bx = r * 8 + (w2 & 7);
        by = xcd * 8 + (w2 >> 3);
        bz = 0;
    } else {
        bx = blockIdx.x; by = blockIdx.y; bz = blockIdx.z;
    }
    if (MODE == 1 && bx > by) return;
    if (MODE == 2) { bz = blockIdx.y & 3; by = 15 - (int)(blockIdx.y >> 2); }
    A += (size_t)bz * sA; B += (size_t)bz * sB; C += (size_t)bz * sC;
    int kend = K;
    if (MODE == 2) { int kl = (by + 1) * 128; kend = kl < K ? kl : K; }
    const int NT = kend >> 6;              // K-steps of 64

    __shared__ u16 lds[32768];             // 2 bufs x [A 8192 u16 | B 8192 u16]

    const int tid  = threadIdx.x;
    const int lane = tid & 63;
    const int wave = tid >> 6;             // 0..3
    const int wr = (wave >> 1) * 64;       // 0 or 64
    const int wc = (wave & 1) * 64;        // 0 or 64
    const int fr = lane & 15;
    const int fq = lane >> 4;
    const int tm = by * 128, tn = bx * 128;

    // staging: 8 x 16B per thread per K-step (4 A + 4 B chunks of 32 rows),
    // pre-swizzled source col (both-sides rule). srow covers rows 0..31 per chunk.
    const int srow = tid >> 3;                                  // 0..31
    const int gco  = (((tid & 7) ^ (srow & 7)) << 3);           // u16 col
    const u16* aR[4]; const u16* bR[4];
#pragma unroll
    for (int j = 0; j < 4; ++j) {
        aR[j] = A + (size_t)(tm + j * 32 + srow) * lda + gco;
        bR[j] = B + (size_t)(tn + j * 32 + srow) * ldb + gco;
    }

#define STAGE(b2, k0) do {                                                        \
    _Pragma("unroll") for (int j = 0; j < 4; ++j)                                 \
        gl_lds16(aR[j] + (k0), lds + (b2) * 16384 + j * 2048 + tid * 8);          \
    _Pragma("unroll") for (int j = 0; j < 4; ++j)                                 \
        gl_lds16(bR[j] + (k0), lds + (b2) * 16384 + 8192 + j * 2048 + tid * 8);   \
  } while (0)

    f32x4 acc[4][4];
#pragma unroll
    for (int m = 0; m < 4; ++m)
#pragma unroll
        for (int n = 0; n < 4; ++n) acc[m][n] = {0.f, 0.f, 0.f, 0.f};

    STAGE(0, 0);
    if (NT > 1) STAGE(1, 64);

    for (int t = 0; t < NT; ++t) {
        const int buf = t & 1;
        if (t + 1 < NT) { asm volatile("s_waitcnt vmcnt(8)" ::: "memory"); }
        else            { asm volatile("s_waitcnt vmcnt(0)" ::: "memory"); }
        __builtin_amdgcn_s_barrier();
        __builtin_amdgcn_sched_barrier(0);

        const u16* Ab = lds + buf * 16384;
        const u16* Bb = Ab + 8192;
        s16x8 bf0[4], bf1[4];
#pragma unroll
        for (int n = 0; n < 4; ++n) {
            bf0[n] = ldfrag(Bb, wc + n * 16 + fr, 0, fq);
            bf1[n] = ldfrag(Bb, wc + n * 16 + fr, 1, fq);
        }
        __builtin_amdgcn_s_setprio(1);
#pragma unroll
        for (int m = 0; m < 4; ++m) {
            s16x8 a0 = ldfrag(Ab, wr + m * 16 + fr, 0, fq);
            s16x8 a1 = ldfrag(Ab, wr + m * 16 + fr, 1, fq);
#pragma unroll
            for (int n = 0; n < 4; ++n) {
                acc[m][n] = MFMA16(a0, bf0[n], acc[m][n]);
                acc[m][n] = MFMA16(a1, bf1[n], acc[m][n]);
            }
        }
        __builtin_amdgcn_s_setprio(0);
        __builtin_amdgcn_sched_barrier(0);
        __builtin_amdgcn_s_barrier();
        if (t + 2 < NT) STAGE(buf, (t + 2) << 6);
    }
#undef STAGE

    // epilogue: D row=(lane>>4)*4+r, col=lane&15 (m89-verified)
    if (MODE == 0 && tn >= 2048) {
        // V column-tiles: write transposed into VT[b][col-2048][t]
#pragma unroll
        for (int m = 0; m < 4; ++m)
#pragma unroll
            for (int n = 0; n < 4; ++n)
#pragma unroll
                for (int r = 0; r < 4; ++r) {
                    int row = tm + wr + m * 16 + fq * 4 + r;
                    int col = tn + wc + n * 16 + fr;
                    VT[((size_t)(row >> 11)) * 2097152 + (size_t)(col - 2048) * 2048 + (row & 2047)]
                        = f2bf(acc[m][n][r]);
                }
    } else {
#pragma unroll
        for (int m = 0; m < 4; ++m)
#pragma unroll
            for (int n = 0; n < 4; ++n)
#pragma unroll
                for (int r = 0; r < 4; ++r) {
                    int row = tm + wr + m * 16 + fq * 4 + r;
                    int col = tn + wc + n * 16 + fr;
                    store_c(&C[(size_t)row * ldc + col], acc[m][n][r]);
                }
    }
}

// ---------- RoPE + L2 norm * sqk*32, in-place on qk[8192][2048] ----------
__global__ __launch_bounds__(256)
void rope_norm(u16* __restrict__ qk, const float* __restrict__ sqk,
               const u16* __restrict__ trig) {
    const int row = blockIdx.x;        // b*2048 + t
    const int t = row & 2047;
    u16* qp = qk + (size_t)row * 2048;
    u16* kp = qp + 1024;
    const u16* tb = trig + (size_t)t * 1024;
    const int d = threadIdx.x << 1;    // 0,2,...,510

    union U2 { uint u; u16 h[2]; };
    U2 qc0, qc1, kc0, kc1, cc, ss;
    qc0.u = *reinterpret_cast<const uint*>(qp + d);
    qc1.u = *reinterpret_cast<const uint*>(qp + 512 + d);
    kc0.u = *reinterpret_cast<const uint*>(kp + d);
    kc1.u = *reinterpret_cast<const uint*>(kp + 512 + d);
    cc.u  = *reinterpret_cast<const uint*>(tb + d);
    ss.u  = *reinterpret_cast<const uint*>(tb + 512 + d);

    float nq0[2], nq1[2], nk0[2], nk1[2];
    float ssq_q = 0.f, ssq_k = 0.f;
#pragma unroll
    for (int j = 0; j < 2; ++j) {
        float c = h2f(cc.h[j]), s = h2f(ss.h[j]);
        float q0 = bf2f(qc0.h[j]), q1 = bf2f(qc1.h[j]);
        float k0 = bf2f(kc0.h[j]), k1 = bf2f(kc1.h[j]);
        nq0[j] = q0 * c - q1 * s;
        nq1[j] = q1 * c + q0 * s;
        nk0[j] = k0 * c - k1 * s;
        nk1[j] = k1 * c + k0 * s;
        ssq_q += nq0[j] * nq0[j] + nq1[j] * nq1[j];
        ssq_k += nk0[j] * nk0[j] + nk1[j] * nk1[j];
    }

#pragma unroll
    for (int off = 32; off; off >>= 1) {
        ssq_q += __shfl_xor(ssq_q, off);
        ssq_k += __shfl_xor(ssq_k, off);
    }
    __shared__ float red[8];
    int wave = threadIdx.x >> 6, lane = threadIdx.x & 63;
    if (lane == 0) { red[wave] = ssq_q; red[4 + wave] = ssq_k; }
    __syncthreads();
    float rq = rsqrtf(red[0] + red[1] + red[2] + red[3]);
    float rk = rsqrtf(red[4] + red[5] + red[6] + red[7]);

    float2 sq0 = *reinterpret_cast<const float2*>(sqk + d);
    float2 sq1 = *reinterpret_cast<const float2*>(sqk + 512 + d);
    float s0[2] = {sq0.x * 32.f, sq0.y * 32.f};
    float s1[2] = {sq1.x * 32.f, sq1.y * 32.f};

    U2 oq0, oq1, ok0, ok1;
#pragma unroll
    for (int j = 0; j < 2; ++j) {
        oq0.h[j] = f2bf(nq0[j] * rq * s0[j]);
        oq1.h[j] = f2bf(nq1[j] * rq * s1[j]);
        ok0.h[j] = f2bf(nk0[j] * rk * s0[j]);
        ok1.h[j] = f2bf(nk1[j] * rk * s1[j]);
    }
    *reinterpret_cast<uint*>(qp + d)       = oq0.u;
    *reinterpret_cast<uint*>(qp + 512 + d) = oq1.u;
    *reinterpret_cast<uint*>(kp + d)       = ok0.u;
    *reinterpret_cast<uint*>(kp + 512 + d) = ok1.u;
}

// ---------- in-place causal softmax over fp16 S rows -> bf16 P (same bytes) ----------
// Writes cols [0, ((r>>7)+1)*128) — 128-granular, matching PV's 128-row K limits.
__global__ __launch_bounds__(256)
void softmax_inplace(u16* __restrict__ Sbase) {
    const int r = blockIdx.x;
    const int b = blockIdx.y;
    u16* row = Sbase + (size_t)b * 4194304 + (size_t)r * 2048;
    const int n = r + 1;
    const int kcap = ((r >> 7) + 1) << 7;
    const int tid = threadIdx.x;
    const bool act = (tid * 8) < kcap;

    union { uint4 u; u16 h[8]; } U;
    if (act) U.u = *reinterpret_cast<const uint4*>(row + tid * 8);
    float v[8];
    float m = -1e30f;
#pragma unroll
    for (int i = 0; i < 8; ++i) {
        int c = tid * 8 + i;
        v[i] = (act && c < n) ? h2f(U.h[i]) : -1e30f;
        m = fmaxf(m, v[i]);
    }
#pragma unroll
    for (int off = 32; off; off >>= 1) m = fmaxf(m, __shfl_xor(m, off));
    __shared__ float redm[4], redsum[4];
    int wave = tid >> 6, lane = tid & 63;
    if (lane == 0) redm[wave] = m;
    __syncthreads();
    m = fmaxf(fmaxf(redm[0], redm[1]), fmaxf(redm[2], redm[3]));
    float M = 32.f * m;

    float sum = 0.f;
#pragma unroll
    for (int i = 0; i < 8; ++i) {
        int c = tid * 8 + i;
        float e = (v[i] > -1e29f) ? __expf(32.f * v[i] - M) : 0.f;
        if (c >= n) e = 0.f;
        v[i] = e;
        sum += e;
    }
#pragma unroll
    for (int off = 32; off; off >>= 1) sum += __shfl_xor(sum, off);
    if (lane == 0) redsum[wave] = sum;
    __syncthreads();
    sum = redsum[0] + redsum[1] + redsum[2] + redsum[3];
    float inv = 1.f / sum;

    if (act) {
        union { uint4 u; u16 h[8]; } O;
#pragma unroll
        for (int i = 0; i < 8; ++i) O.h[i] = f2bf(v[i] * inv);
        *reinterpret_cast<uint4*>(row + tid * 8) = O.u;
    }
}

// ---------- host launcher ----------
extern "C" void kernel_launch(void* const* d_in, const int* in_sizes, int n_in,
                              void* d_out, int out_size, void* d_ws, size_t ws_size,
                              hipStream_t stream) {
    const float* x   = (const float*)d_in[0];   // [4,2048,1024]
    const float* w   = (const float*)d_in[1];   // [3072,1024]
    const float* sqk = (const float*)d_in[2];   // [1024]
    float* out = (float*)d_out;

    const size_t SZ_XB  = (size_t)8192 * 1024 * 2;
    const size_t SZ_WB  = (size_t)3072 * 1024 * 2;
    const size_t SZ_QK  = (size_t)8192 * 2048 * 2;
    const size_t SZ_VT  = (size_t)4 * 1024 * 2048 * 2;
    const size_t SZ_S   = (size_t)4 * 2048 * 2048 * 2;    // fp16
    const size_t SZ_TR  = (size_t)2048 * 1024 * 2;
    if (ws_size < SZ_XB + SZ_WB + SZ_QK + SZ_VT + SZ_S + SZ_TR) return;

    char* ws = (char*)d_ws;
    u16* xb   = (u16*)ws;  ws += SZ_XB;
    u16* wb   = (u16*)ws;  ws += SZ_WB;
    u16* qk   = (u16*)ws;  ws += SZ_QK;
    u16* VT   = (u16*)ws;  ws += SZ_VT;
    u16* S    = (u16*)ws;  ws += SZ_S;
    u16* trig = (u16*)ws;

    // fused prep: x->bf16, w->bf16, trig table
    prep<<<4864, 256, 0, stream>>>(x, w, xb, wb, trig);

    // QKV: qk[8192][2048] (Q|K) + VT[b][1024][2048] (V^T direct)
    gemm_bt<0, u16><<<dim3(1536, 1, 1), 256, 0, stream>>>(
        xb, wb, qk, VT, 1024, 1024, 1024, 2048, 0, 0, 0);

    rope_norm<<<8192, 256, 0, stream>>>(qk, sqk, trig);

    // S = Q @ K^T, causal 128^2 tiles, fp16
    gemm_bt<1, _Float16><<<dim3(16, 16, 4), 256, 0, stream>>>(
        qk, qk + 1024, (_Float16*)S, nullptr, 1024, 2048, 2048, 2048,
        (long)2048 * 2048, (long)2048 * 2048, (long)2048 * 2048);

    softmax_inplace<<<dim3(2048, 4), 256, 0, stream>>>(S);

    // out = P @ V, 128^2 tiles, longest-first over row tiles
    gemm_bt<2, float><<<dim3(8, 64, 1), 256, 0, stream>>>(
        S, VT, out, nullptr, 2048, 2048, 2048, 1024,
        (long)2048 * 2048, (long)1024 * 2048, (long)2048 * 1024);
}